// Round 12
// baseline (1942.221 us; speedup 1.0000x reference)
//
#include <hip/hip_runtime.h>
#include <hip/hip_bf16.h>
#include <stdint.h>

typedef __bf16 bf16x8 __attribute__((ext_vector_type(8)));
typedef float  f32x4  __attribute__((ext_vector_type(4)));
typedef unsigned short ushort8v __attribute__((ext_vector_type(8)));

#define NH      4096
#define MB      1024
#define M2      2048
#define DIN     784
#define KPAD    832      /* 26*32 */
#define N_IN    8192
#define NLAYERS 24
#define NOUT    10

// GEMM geometry: 128x128 tile, BK=32, 4 waves (2M x 2N), 64x64/wave,
// 16x16x32 MFMA. LDS: 5-slot ring, slot = A[128][32]+B[128][32] = 16 KB
// -> 80 KB total -> exactly 2 blocks/CU. Counted vmcnt: depth-3 prefetch,
// steady-state wait vmcnt(8) (retire exactly one tile), never 0 mid-loop.
#define ASL32   (128 * 32)            /* 4096 elements */
#define SLOT    (2 * ASL32)           /* 8192 elements = 16 KB */

__device__ __forceinline__ unsigned short f2bf(float x) {
  union { float f; unsigned u; } v; v.f = x;
  unsigned r = v.u + 0x7FFFu + ((v.u >> 16) & 1u);   // RNE (finite inputs)
  return (unsigned short)(r >> 16);
}
__device__ __forceinline__ float bf2f(unsigned short u) {
  union { unsigned u; float f; } v; v.u = ((unsigned)u) << 16; return v.f;
}
__device__ __forceinline__ int swz5(int row) {       // 64B-row bank swizzle
  return (row & 3) ^ ((row >> 2) & 3);
}

__device__ __forceinline__ void async16(const void* g, void* l) {
  __builtin_amdgcn_global_load_lds(
      (const __attribute__((address_space(1))) void*)g,
      (__attribute__((address_space(3))) void*)l, 16, 0, 0);
}

// ---------- weight conversion: fold o into W_sp ----------
__global__ void k_conv_wsp(const float* __restrict__ W, const float* __restrict__ o,
                           unsigned short* __restrict__ out) {
  size_t i = ((size_t)blockIdx.x * blockDim.x + threadIdx.x) * 4;
  if (i >= (size_t)NH * NH) return;
  float4 w = *reinterpret_cast<const float4*>(W + i);
  int k = (int)(i & (NH - 1));
  float4 ov = *reinterpret_cast<const float4*>(o + k);
  ushort4 r;
  r.x = f2bf(w.x * ov.x); r.y = f2bf(w.y * ov.y);
  r.z = f2bf(w.z * ov.z); r.w = f2bf(w.w * ov.w);
  *reinterpret_cast<ushort4*>(out + i) = r;
}

// ---------- fused pad+convert for W_in and x ----------
__global__ void k_conv_pad2(const float* __restrict__ Win, const float* __restrict__ x,
                            unsigned short* __restrict__ Win_bf,
                            unsigned short* __restrict__ X_bf) {
  size_t i = (size_t)blockIdx.x * blockDim.x + threadIdx.x;
  if (i >= (size_t)(N_IN + MB) * KPAD) return;
  int r = (int)(i / KPAD), c = (int)(i % KPAD);
  if (r < N_IN) Win_bf[i] = (c < DIN) ? f2bf(Win[(size_t)r * DIN + c]) : (unsigned short)0;
  else {
    int rr = r - N_IN;
    X_bf[(size_t)rr * KPAD + c] = (c < DIN) ? f2bf(x[(size_t)rr * DIN + c]) : (unsigned short)0;
  }
}

// ---------- 128x128 GEMM core: 5-slot ring, BK=32, counted vmcnt ----------
__device__ __forceinline__ void gemm_core(
    const unsigned short* __restrict__ Ag, const unsigned short* __restrict__ Bg,
    int K, int bm, int bn, unsigned short* lds, f32x4 acc[4][4])
{
  const int t    = threadIdx.x;
  const int lane = t & 63;
  const int wave = t >> 6;           // 0..3
  const int wm   = wave >> 1;        // 64-row band
  const int wn   = wave & 1;         // 64-col band
  const int l15  = lane & 15;
  const int sk   = lane >> 4;        // 16B k-slot (8 elements)

  // ---- staging: chunk c = j*256+t (16B); row=c>>2, slot=c&3; linear dest,
  // pre-swizzled source col-slot (cs ^ swz5(row)) ----
  unsigned aGo[2], bGo[2]; int dL[2];
#pragma unroll
  for (int j = 0; j < 2; ++j) {
    const int c   = j * 256 + t;
    const int row = c >> 2;
    const int cs  = (c & 3) ^ swz5(row);
    dL[j]  = c * 8;                                    // element offset in slot
    aGo[j] = (unsigned)((bm + row) * K + cs * 8);
    bGo[j] = (unsigned)((bn + row) * K + cs * 8);
  }

  auto STAGE = [&](int slotIdx, int k0) {              // 4 async16/thread
    unsigned short* s = lds + slotIdx * SLOT;
#pragma unroll
    for (int j = 0; j < 2; ++j) {
      async16(Ag + aGo[j] + (unsigned)k0, s + dL[j]);
      async16(Bg + bGo[j] + (unsigned)k0, s + ASL32 + dL[j]);
    }
  };

  // ---- fragment read offsets (elements within slot) ----
  int aRd[4], bRd[4];
#pragma unroll
  for (int i = 0; i < 4; ++i) {
    const int ra = wm * 64 + i * 16 + l15;
    aRd[i] = ra * 32 + ((sk ^ swz5(ra)) * 8);
    const int rb = wn * 64 + i * 16 + l15;
    bRd[i] = rb * 32 + ((sk ^ swz5(rb)) * 8);
  }

  const int nt = K >> 5;
  STAGE(0, 0);
  if (nt > 1) STAGE(1, 32);
  if (nt > 2) STAGE(2, 64);

  int s0 = 0, s3 = 3;                // kt % 5, (kt+3) % 5
  for (int kt = 0; kt < nt; ++kt) {
    const int rem = nt - 1 - kt;
    if (rem >= 2)      asm volatile("s_waitcnt vmcnt(8)" ::: "memory");
    else if (rem == 1) asm volatile("s_waitcnt vmcnt(4)" ::: "memory");
    else               asm volatile("s_waitcnt vmcnt(0)" ::: "memory");
    __builtin_amdgcn_s_barrier();                      // tile kt visible
    if (kt + 3 < nt) STAGE(s3, (kt + 3) << 5);
    const unsigned short* base = lds + s0 * SLOT;
    __builtin_amdgcn_s_setprio(1);
    bf16x8 a[4], b[4];
#pragma unroll
    for (int i = 0; i < 4; ++i) a[i] = *reinterpret_cast<const bf16x8*>(base + aRd[i]);
#pragma unroll
    for (int i = 0; i < 4; ++i) b[i] = *reinterpret_cast<const bf16x8*>(base + ASL32 + bRd[i]);
#pragma unroll
    for (int mi = 0; mi < 4; ++mi)
#pragma unroll
      for (int ni = 0; ni < 4; ++ni)
        acc[mi][ni] = __builtin_amdgcn_mfma_f32_16x16x32_bf16(a[mi], b[ni], acc[mi][ni], 0, 0, 0);
    __builtin_amdgcn_s_setprio(0);
    s0 = (s0 == 4) ? 0 : s0 + 1;
    s3 = (s3 == 4) ? 0 : s3 + 1;
  }
}

// ---------- recurrent layer GEMM ----------
__global__ __launch_bounds__(256, 2) void k_gemm_layer(
    const unsigned short* __restrict__ A, const unsigned short* __restrict__ W,
    const float* __restrict__ bias, float* __restrict__ preact,
    unsigned short* __restrict__ Anext)
{
  __shared__ __align__(16) unsigned short lds[5 * SLOT];   // 80 KB
  const int bid = blockIdx.x;            // 512 blocks = 16 bm x 32 bn
  const int xcd = bid & 7;
  const int idx = bid >> 3;              // 0..63
  const int bm  = (idx >> 2) * 128;      // 16 m-bands
  const int bn  = (xcd * 4 + (idx & 3)) * 128;   // XCD owns 4 bn-bands (W L2-fit)
  f32x4 acc[4][4] = {};
  gemm_core(A, W, NH, bm, bn, lds, acc);

  const int lane = threadIdx.x & 63;
  const int wave = threadIdx.x >> 6;
  const int wm = (wave >> 1) * 64, wn = (wave & 1) * 64;
  const int l15 = lane & 15;
#pragma unroll
  for (int mi = 0; mi < 4; ++mi) {
    const int gm0 = bm + wm + mi * 16 + (lane >> 4) * 4;   // C/D: row=(lane>>4)*4+r
#pragma unroll
    for (int ni = 0; ni < 4; ++ni) {
      const int gn = bn + wn + ni * 16 + l15;              // C/D: col=lane&15
      const float bv = bias[gn];
#pragma unroll
      for (int r = 0; r < 4; ++r) {
        const int gm = gm0 + r;
        const float y = acc[mi][ni][r] + bv;
        if (gm < MB) preact[(size_t)gm * NH + gn] = y;
        Anext[(size_t)gm * NH + gn] = f2bf(y > 0.f ? y : 0.f);
      }
    }
  }
}

// ---------- input GEMM ----------
__global__ __launch_bounds__(256, 2) void k_gemm_in(
    const unsigned short* __restrict__ X, const unsigned short* __restrict__ W,
    const float* __restrict__ bias, float* __restrict__ preact0,
    unsigned short* __restrict__ A0)
{
  __shared__ __align__(16) unsigned short lds[5 * SLOT];
  const int bid = blockIdx.x;            // 512 blocks = 8 bm x 64 bn
  const int xcd = bid & 7;
  const int idx = bid >> 3;              // 0..63
  const int bm  = (idx >> 3) * 128;      // 8 m-bands
  const int bn  = (xcd * 8 + (idx & 7)) * 128;
  f32x4 acc[4][4] = {};
  gemm_core(X, W, KPAD, bm, bn, lds, acc);

  const int lane = threadIdx.x & 63;
  const int wave = threadIdx.x >> 6;
  const int wm = (wave >> 1) * 64, wn = (wave & 1) * 64;
  const int l15 = lane & 15;
#pragma unroll
  for (int mi = 0; mi < 4; ++mi) {
    const int gm0 = bm + wm + mi * 16 + (lane >> 4) * 4;
#pragma unroll
    for (int ni = 0; ni < 4; ++ni) {
      const int gn = bn + wn + ni * 16 + l15;
      const float bv = bias[gn];
#pragma unroll
      for (int r = 0; r < 4; ++r) {
        const int gm = gm0 + r;
        const float y = acc[mi][ni][r] + bv;
        const unsigned short rl = f2bf(y > 0.f ? y : 0.f);
        if (gn < NH) {                       // "a" stream
          preact0[(size_t)gm * NH + gn] = y;
          A0[(size_t)gm * NH + gn] = rl;
        } else {                             // "b" stream -> rows 1024..2047
          A0[(size_t)(MB + gm) * NH + (gn - NH)] = rl;
        }
      }
    }
  }
}

// ---------- final head: 256 blocks x 8 rows, vectorized loads ----------
__global__ __launch_bounds__(256) void k_final(
    const unsigned short* __restrict__ A, const float* __restrict__ Wf,
    const float* __restrict__ of, const float* __restrict__ bf_,
    float* __restrict__ out)
{
  __shared__ float red[4][NOUT];
  const int t = threadIdx.x;
  for (int rr = 0; rr < 8; ++rr) {
    const int m = blockIdx.x * 8 + rr;          // 0..2047
    float accj[NOUT];
#pragma unroll
    for (int j = 0; j < NOUT; ++j) accj[j] = 0.f;
    for (int k0 = t * 8; k0 < NH; k0 += 256 * 8) {
      const ushort8v av = *reinterpret_cast<const ushort8v*>(A + (size_t)m * NH + k0);
      const float4 o0 = *reinterpret_cast<const float4*>(of + k0);
      const float4 o1 = *reinterpret_cast<const float4*>(of + k0 + 4);
      float a[8];
      a[0] = bf2f(av[0]) * o0.x; a[1] = bf2f(av[1]) * o0.y;
      a[2] = bf2f(av[2]) * o0.z; a[3] = bf2f(av[3]) * o0.w;
      a[4] = bf2f(av[4]) * o1.x; a[5] = bf2f(av[5]) * o1.y;
      a[6] = bf2f(av[6]) * o1.z; a[7] = bf2f(av[7]) * o1.w;
#pragma unroll
      for (int j = 0; j < NOUT; ++j) {
        const float4 w0 = *reinterpret_cast<const float4*>(Wf + (size_t)j * NH + k0);
        const float4 w1 = *reinterpret_cast<const float4*>(Wf + (size_t)j * NH + k0 + 4);
        accj[j] += a[0]*w0.x + a[1]*w0.y + a[2]*w0.z + a[3]*w0.w
                 + a[4]*w1.x + a[5]*w1.y + a[6]*w1.z + a[7]*w1.w;
      }
    }
#pragma unroll
    for (int j = 0; j < NOUT; ++j) {
      float v = accj[j];
      for (int off = 32; off > 0; off >>= 1) v += __shfl_down(v, off);
      if ((t & 63) == 0) red[t >> 6][j] = v;
    }
    __syncthreads();
    if (t < NOUT)
      out[(size_t)m * NOUT + t] = red[0][t] + red[1][t] + red[2][t] + red[3][t] + bf_[t];
    __syncthreads();
  }
}

extern "C" void kernel_launch(void* const* d_in, const int* in_sizes, int n_in,
                              void* d_out, int out_size, void* d_ws, size_t ws_size,
                              hipStream_t stream) {
  const float* x     = (const float*)d_in[0];
  const float* W_in  = (const float*)d_in[1];
  const float* b_in  = (const float*)d_in[2];
  const float* keysp = (const float*)d_in[3];
  const float* W_sp  = (const float*)d_in[4];
  const float* b_sp  = (const float*)d_in[5];
  const float* keyf  = (const float*)d_in[6];
  const float* W_f   = (const float*)d_in[7];
  const float* b_f   = (const float*)d_in[8];

  float* out    = (float*)d_out;
  float* preact = out + (size_t)2 * MB * NOUT;  // 25 x 1024 x 4096

  char* ws = (char*)d_ws;
  unsigned short* Wsp_bf = (unsigned short*)ws;  ws += (size_t)NH * NH * 2;
  unsigned short* A0     = (unsigned short*)ws;  ws += (size_t)M2 * NH * 2;
  unsigned short* A1     = (unsigned short*)ws;  ws += (size_t)M2 * NH * 2;
  unsigned short* Win_bf = (unsigned short*)ws;  ws += (size_t)N_IN * KPAD * 2;
  unsigned short* X_bf   = (unsigned short*)ws;  ws += (size_t)MB * KPAD * 2;

  k_conv_wsp<<<(NH * (size_t)NH / 4 + 255) / 256, 256, 0, stream>>>(W_sp, keysp, Wsp_bf);
  k_conv_pad2<<<((size_t)(N_IN + MB) * KPAD + 255) / 256, 256, 0, stream>>>(
      W_in, x, Win_bf, X_bf);

  // input GEMM: M=1024, N=8192, K=832 -> 8*64 = 512 blocks
  k_gemm_in<<<512, 256, 0, stream>>>(X_bf, Win_bf, b_in, preact, A0);

  // 24 recurrent layers: M=2048, N=4096, K=4096 -> 16*32 = 512 blocks
  unsigned short* Ain = A0;
  unsigned short* Aout = A1;
  for (int tlay = 0; tlay < NLAYERS; ++tlay) {
    float* pre = preact + (size_t)(tlay + 1) * MB * NH;
    k_gemm_layer<<<512, 256, 0, stream>>>(Ain, Wsp_bf, b_sp, pre, Aout);
    unsigned short* tmp = Ain; Ain = Aout; Aout = tmp;
  }

  k_final<<<M2 / 8, 256, 0, stream>>>(Ain, W_f, keyf, b_f, out);
}

// Round 13
// 1593.414 us; speedup vs baseline: 1.2189x; 1.2189x over previous
//
#include <hip/hip_runtime.h>
#include <hip/hip_bf16.h>
#include <stdint.h>

typedef __bf16 bf16x8 __attribute__((ext_vector_type(8)));
typedef float  f32x4  __attribute__((ext_vector_type(4)));
typedef unsigned short ushort8v __attribute__((ext_vector_type(8)));

#define NH      4096
#define MB      1024
#define M2      2048
#define DIN     784
#define KPAD    832      /* 13*64 */
#define N_IN    8192
#define NLAYERS 24
#define NOUT    10

// GEMM geometry (R9 best): 128x128 tile, BK=64, 4 waves (2M x 2N), 64x64/wave,
// 16x16x32 MFMA, 2-slot double buffer (64 KB) -> 2 blocks/CU.
// R13 variant: preload ALL 16 fragments per tile in one ds_read burst, then
// STAGE(next), then one 32-MFMA cluster (single big sched window per tile).
#define ASL     (128 * 64)            /* elements */
#define SLOT    (2 * ASL)             /* 16384 elements = 32 KB */

__device__ __forceinline__ unsigned short f2bf(float x) {
  union { float f; unsigned u; } v; v.f = x;
  unsigned r = v.u + 0x7FFFu + ((v.u >> 16) & 1u);   // RNE (finite inputs)
  return (unsigned short)(r >> 16);
}
__device__ __forceinline__ float bf2f(unsigned short u) {
  union { unsigned u; float f; } v; v.u = ((unsigned)u) << 16; return v.f;
}

__device__ __forceinline__ void async16(const void* g, void* l) {
  __builtin_amdgcn_global_load_lds(
      (const __attribute__((address_space(1))) void*)g,
      (__attribute__((address_space(3))) void*)l, 16, 0, 0);
}

// ---------- weight conversion: fold o into W_sp ----------
__global__ void k_conv_wsp(const float* __restrict__ W, const float* __restrict__ o,
                           unsigned short* __restrict__ out) {
  size_t i = ((size_t)blockIdx.x * blockDim.x + threadIdx.x) * 4;
  if (i >= (size_t)NH * NH) return;
  float4 w = *reinterpret_cast<const float4*>(W + i);
  int k = (int)(i & (NH - 1));
  float4 ov = *reinterpret_cast<const float4*>(o + k);
  ushort4 r;
  r.x = f2bf(w.x * ov.x); r.y = f2bf(w.y * ov.y);
  r.z = f2bf(w.z * ov.z); r.w = f2bf(w.w * ov.w);
  *reinterpret_cast<ushort4*>(out + i) = r;
}

// ---------- fused pad+convert for W_in and x ----------
__global__ void k_conv_pad2(const float* __restrict__ Win, const float* __restrict__ x,
                            unsigned short* __restrict__ Win_bf,
                            unsigned short* __restrict__ X_bf) {
  size_t i = (size_t)blockIdx.x * blockDim.x + threadIdx.x;
  if (i >= (size_t)(N_IN + MB) * KPAD) return;
  int r = (int)(i / KPAD), c = (int)(i % KPAD);
  if (r < N_IN) Win_bf[i] = (c < DIN) ? f2bf(Win[(size_t)r * DIN + c]) : (unsigned short)0;
  else {
    int rr = r - N_IN;
    X_bf[(size_t)rr * KPAD + c] = (c < DIN) ? f2bf(x[(size_t)rr * DIN + c]) : (unsigned short)0;
  }
}

// ---------- 128x128 double-buffered GEMM core ----------
__device__ __forceinline__ void gemm_core(
    const unsigned short* __restrict__ Ag, const unsigned short* __restrict__ Bg,
    int K, int bm, int bn, unsigned short* lds, f32x4 acc[4][4])
{
  const int t    = threadIdx.x;
  const int lane = t & 63;
  const int wave = t >> 6;           // 0..3
  const int wm   = wave >> 1;        // 64-row band
  const int wn   = wave & 1;         // 64-col band
  const int l15  = lane & 15;
  const int lkb  = (lane >> 4) * 16; // byte offset of k-group within row

  const int srow = t >> 3;
  const int sb   = ((t & 7) * 16) ^ ((srow & 7) << 4);
  const unsigned aG0 = (unsigned)((bm + srow) * K + (sb >> 1));
  const unsigned bG0 = (unsigned)((bn + srow) * K + (sb >> 1));

  auto STAGE = [&](int bufIdx, int k0) {
    unsigned short* s = lds + bufIdx * SLOT;
#pragma unroll
    for (int j = 0; j < 4; ++j)
      async16(Ag + aG0 + (unsigned)(j * 32 * K + k0), s + t * 8 + j * 2048);
#pragma unroll
    for (int j = 0; j < 4; ++j)
      async16(Bg + bG0 + (unsigned)(j * 32 * K + k0), s + ASL + t * 8 + j * 2048);
  };

  int aRd[2][4], bRd[2][4];
#pragma unroll
  for (int kk = 0; kk < 2; ++kk)
#pragma unroll
    for (int i = 0; i < 4; ++i) {
      const int ra = wm * 64 + i * 16 + l15;
      aRd[kk][i] = (ra * 128 + ((kk * 64 + lkb) ^ ((ra & 7) << 4))) >> 1;
      const int rb = wn * 64 + i * 16 + l15;
      bRd[kk][i] = (rb * 128 + ((kk * 64 + lkb) ^ ((rb & 7) << 4))) >> 1;
    }

  const int nt = K >> 6;
  STAGE(0, 0);
  asm volatile("s_waitcnt vmcnt(0)" ::: "memory");
  __builtin_amdgcn_s_barrier();

  int buf = 0;
  for (int kt = 0; kt < nt; ++kt) {
    const unsigned short* base = lds + buf * SLOT;
    // --- preload ALL fragments for this tile (one ds_read burst) ---
    bf16x8 a[2][4], b[2][4];
#pragma unroll
    for (int kk = 0; kk < 2; ++kk) {
#pragma unroll
      for (int i = 0; i < 4; ++i) a[kk][i] = *reinterpret_cast<const bf16x8*>(base + aRd[kk][i]);
#pragma unroll
      for (int i = 0; i < 4; ++i) b[kk][i] = *reinterpret_cast<const bf16x8*>(base + ASL + bRd[kk][i]);
    }
    // --- issue next-tile stage while reads are in flight ---
    if (kt + 1 < nt) STAGE(buf ^ 1, (kt + 1) << 6);
    // --- one big MFMA cluster (compiler inserts fine-grained lgkmcnt) ---
    __builtin_amdgcn_s_setprio(1);
#pragma unroll
    for (int kk = 0; kk < 2; ++kk)
#pragma unroll
      for (int mi = 0; mi < 4; ++mi)
#pragma unroll
        for (int ni = 0; ni < 4; ++ni)
          acc[mi][ni] = __builtin_amdgcn_mfma_f32_16x16x32_bf16(a[kk][mi], b[kk][ni], acc[mi][ni], 0, 0, 0);
    __builtin_amdgcn_s_setprio(0);
    if (kt + 1 < nt) {
      asm volatile("s_waitcnt vmcnt(0)" ::: "memory");  // next buf fully written
      __builtin_amdgcn_s_barrier();                     // my reads also retired
    }
    buf ^= 1;
  }
}

// ---------- recurrent layer GEMM ----------
__global__ __launch_bounds__(256, 2) void k_gemm_layer(
    const unsigned short* __restrict__ A, const unsigned short* __restrict__ W,
    const float* __restrict__ bias, float* __restrict__ preact,
    unsigned short* __restrict__ Anext)
{
  __shared__ __align__(16) unsigned short lds[2 * SLOT];   // 64 KB
  const int bid = blockIdx.x;            // 512 blocks = 16 bm x 32 bn
  const int xcd = bid & 7;
  const int idx = bid >> 3;              // 0..63
  const int bm  = (idx >> 2) * 128;      // 16 m-bands
  const int bn  = (xcd * 4 + (idx & 3)) * 128;   // XCD owns 4 bn-bands (W L2-fit)
  f32x4 acc[4][4] = {};
  gemm_core(A, W, NH, bm, bn, lds, acc);

  const int lane = threadIdx.x & 63;
  const int wave = threadIdx.x >> 6;
  const int wm = (wave >> 1) * 64, wn = (wave & 1) * 64;
  const int l15 = lane & 15;
#pragma unroll
  for (int mi = 0; mi < 4; ++mi) {
    const int gm0 = bm + wm + mi * 16 + (lane >> 4) * 4;   // C/D: row=(lane>>4)*4+r
#pragma unroll
    for (int ni = 0; ni < 4; ++ni) {
      const int gn = bn + wn + ni * 16 + l15;              // C/D: col=lane&15
      const float bv = bias[gn];
#pragma unroll
      for (int r = 0; r < 4; ++r) {
        const int gm = gm0 + r;
        const float y = acc[mi][ni][r] + bv;
        if (gm < MB) preact[(size_t)gm * NH + gn] = y;
        Anext[(size_t)gm * NH + gn] = f2bf(y > 0.f ? y : 0.f);
      }
    }
  }
}

// ---------- input GEMM ----------
__global__ __launch_bounds__(256, 2) void k_gemm_in(
    const unsigned short* __restrict__ X, const unsigned short* __restrict__ W,
    const float* __restrict__ bias, float* __restrict__ preact0,
    unsigned short* __restrict__ A0)
{
  __shared__ __align__(16) unsigned short lds[2 * SLOT];
  const int bid = blockIdx.x;            // 512 blocks = 8 bm x 64 bn
  const int xcd = bid & 7;
  const int idx = bid >> 3;              // 0..63
  const int bm  = (idx >> 3) * 128;      // 8 m-bands
  const int bn  = (xcd * 8 + (idx & 7)) * 128;
  f32x4 acc[4][4] = {};
  gemm_core(X, W, KPAD, bm, bn, lds, acc);

  const int lane = threadIdx.x & 63;
  const int wave = threadIdx.x >> 6;
  const int wm = (wave >> 1) * 64, wn = (wave & 1) * 64;
  const int l15 = lane & 15;
#pragma unroll
  for (int mi = 0; mi < 4; ++mi) {
    const int gm0 = bm + wm + mi * 16 + (lane >> 4) * 4;
#pragma unroll
    for (int ni = 0; ni < 4; ++ni) {
      const int gn = bn + wn + ni * 16 + l15;
      const float bv = bias[gn];
#pragma unroll
      for (int r = 0; r < 4; ++r) {
        const int gm = gm0 + r;
        const float y = acc[mi][ni][r] + bv;
        const unsigned short rl = f2bf(y > 0.f ? y : 0.f);
        if (gn < NH) {                       // "a" stream
          preact0[(size_t)gm * NH + gn] = y;
          A0[(size_t)gm * NH + gn] = rl;
        } else {                             // "b" stream -> rows 1024..2047
          A0[(size_t)(MB + gm) * NH + (gn - NH)] = rl;
        }
      }
    }
  }
}

// ---------- final head: 256 blocks x 8 rows, vectorized loads ----------
__global__ __launch_bounds__(256) void k_final(
    const unsigned short* __restrict__ A, const float* __restrict__ Wf,
    const float* __restrict__ of, const float* __restrict__ bf_,
    float* __restrict__ out)
{
  __shared__ float red[4][NOUT];
  const int t = threadIdx.x;
  for (int rr = 0; rr < 8; ++rr) {
    const int m = blockIdx.x * 8 + rr;          // 0..2047
    float accj[NOUT];
#pragma unroll
    for (int j = 0; j < NOUT; ++j) accj[j] = 0.f;
    for (int k0 = t * 8; k0 < NH; k0 += 256 * 8) {
      const ushort8v av = *reinterpret_cast<const ushort8v*>(A + (size_t)m * NH + k0);
      const float4 o0 = *reinterpret_cast<const float4*>(of + k0);
      const float4 o1 = *reinterpret_cast<const float4*>(of + k0 + 4);
      float a[8];
      a[0] = bf2f(av[0]) * o0.x; a[1] = bf2f(av[1]) * o0.y;
      a[2] = bf2f(av[2]) * o0.z; a[3] = bf2f(av[3]) * o0.w;
      a[4] = bf2f(av[4]) * o1.x; a[5] = bf2f(av[5]) * o1.y;
      a[6] = bf2f(av[6]) * o1.z; a[7] = bf2f(av[7]) * o1.w;
#pragma unroll
      for (int j = 0; j < NOUT; ++j) {
        const float4 w0 = *reinterpret_cast<const float4*>(Wf + (size_t)j * NH + k0);
        const float4 w1 = *reinterpret_cast<const float4*>(Wf + (size_t)j * NH + k0 + 4);
        accj[j] += a[0]*w0.x + a[1]*w0.y + a[2]*w0.z + a[3]*w0.w
                 + a[4]*w1.x + a[5]*w1.y + a[6]*w1.z + a[7]*w1.w;
      }
    }
#pragma unroll
    for (int j = 0; j < NOUT; ++j) {
      float v = accj[j];
      for (int off = 32; off > 0; off >>= 1) v += __shfl_down(v, off);
      if ((t & 63) == 0) red[t >> 6][j] = v;
    }
    __syncthreads();
    if (t < NOUT)
      out[(size_t)m * NOUT + t] = red[0][t] + red[1][t] + red[2][t] + red[3][t] + bf_[t];
    __syncthreads();
  }
}

extern "C" void kernel_launch(void* const* d_in, const int* in_sizes, int n_in,
                              void* d_out, int out_size, void* d_ws, size_t ws_size,
                              hipStream_t stream) {
  const float* x     = (const float*)d_in[0];
  const float* W_in  = (const float*)d_in[1];
  const float* b_in  = (const float*)d_in[2];
  const float* keysp = (const float*)d_in[3];
  const float* W_sp  = (const float*)d_in[4];
  const float* b_sp  = (const float*)d_in[5];
  const float* keyf  = (const float*)d_in[6];
  const float* W_f   = (const float*)d_in[7];
  const float* b_f   = (const float*)d_in[8];

  float* out    = (float*)d_out;
  float* preact = out + (size_t)2 * MB * NOUT;  // 25 x 1024 x 4096

  char* ws = (char*)d_ws;
  unsigned short* Wsp_bf = (unsigned short*)ws;  ws += (size_t)NH * NH * 2;
  unsigned short* A0     = (unsigned short*)ws;  ws += (size_t)M2 * NH * 2;
  unsigned short* A1     = (unsigned short*)ws;  ws += (size_t)M2 * NH * 2;
  unsigned short* Win_bf = (unsigned short*)ws;  ws += (size_t)N_IN * KPAD * 2;
  unsigned short* X_bf   = (unsigned short*)ws;  ws += (size_t)MB * KPAD * 2;

  k_conv_wsp<<<(NH * (size_t)NH / 4 + 255) / 256, 256, 0, stream>>>(W_sp, keysp, Wsp_bf);
  k_conv_pad2<<<((size_t)(N_IN + MB) * KPAD + 255) / 256, 256, 0, stream>>>(
      W_in, x, Win_bf, X_bf);

  // input GEMM: M=1024, N=8192, K=832 -> 8*64 = 512 blocks
  k_gemm_in<<<512, 256, 0, stream>>>(X_bf, Win_bf, b_in, preact, A0);

  // 24 recurrent layers: M=2048, N=4096, K=4096 -> 16*32 = 512 blocks
  unsigned short* Ain = A0;
  unsigned short* Aout = A1;
  for (int tlay = 0; tlay < NLAYERS; ++tlay) {
    float* pre = preact + (size_t)(tlay + 1) * MB * NH;
    k_gemm_layer<<<512, 256, 0, stream>>>(Ain, Wsp_bf, b_sp, pre, Aout);
    unsigned short* tmp = Ain; Ain = Aout; Aout = tmp;
  }

  k_final<<<M2 / 8, 256, 0, stream>>>(Ain, W_f, keyf, b_f, out);
}

// Round 14
// 1519.930 us; speedup vs baseline: 1.2778x; 1.0483x over previous
//
#include <hip/hip_runtime.h>
#include <hip/hip_bf16.h>
#include <stdint.h>

typedef __bf16 bf16x8 __attribute__((ext_vector_type(8)));
typedef float  f32x4  __attribute__((ext_vector_type(4)));
typedef unsigned short ushort8v __attribute__((ext_vector_type(8)));

#define NH      4096
#define MB      1024
#define M2      2048
#define DIN     784
#define KPAD    832      /* 13*64 */
#define N_IN    8192
#define NLAYERS 24
#define NOUT    10

// GEMM geometry: 128x128 tile, BK=64, 4 waves (2M x 2N), 64x64/wave,
// 16x16x32 MFMA. LDS: asymmetric rings — A 3-deep (slow operand, HBM/L3),
// B 2-deep (W panel, L2-resident) = 5 x 16 KB = 80 KB -> exactly 2 blocks/CU.
// Steady-state wait is vmcnt(4) (retire A(kt)+B(kt), keep A(kt+1) in flight)
// -> no full drain at tile boundaries; one barrier per tile.
#define ASLE    8192                  /* elements per 16 KB slot (128x64) */
#define BOFF    (3 * ASLE)            /* B slots start after 3 A slots */

__device__ __forceinline__ unsigned short f2bf(float x) {
  union { float f; unsigned u; } v; v.f = x;
  unsigned r = v.u + 0x7FFFu + ((v.u >> 16) & 1u);   // RNE (finite inputs)
  return (unsigned short)(r >> 16);
}
__device__ __forceinline__ float bf2f(unsigned short u) {
  union { unsigned u; float f; } v; v.u = ((unsigned)u) << 16; return v.f;
}

__device__ __forceinline__ void async16(const void* g, void* l) {
  __builtin_amdgcn_global_load_lds(
      (const __attribute__((address_space(1))) void*)g,
      (__attribute__((address_space(3))) void*)l, 16, 0, 0);
}

// ---------- weight conversion: fold o into W_sp ----------
__global__ void k_conv_wsp(const float* __restrict__ W, const float* __restrict__ o,
                           unsigned short* __restrict__ out) {
  size_t i = ((size_t)blockIdx.x * blockDim.x + threadIdx.x) * 4;
  if (i >= (size_t)NH * NH) return;
  float4 w = *reinterpret_cast<const float4*>(W + i);
  int k = (int)(i & (NH - 1));
  float4 ov = *reinterpret_cast<const float4*>(o + k);
  ushort4 r;
  r.x = f2bf(w.x * ov.x); r.y = f2bf(w.y * ov.y);
  r.z = f2bf(w.z * ov.z); r.w = f2bf(w.w * ov.w);
  *reinterpret_cast<ushort4*>(out + i) = r;
}

// ---------- fused pad+convert for W_in and x ----------
__global__ void k_conv_pad2(const float* __restrict__ Win, const float* __restrict__ x,
                            unsigned short* __restrict__ Win_bf,
                            unsigned short* __restrict__ X_bf) {
  size_t i = (size_t)blockIdx.x * blockDim.x + threadIdx.x;
  if (i >= (size_t)(N_IN + MB) * KPAD) return;
  int r = (int)(i / KPAD), c = (int)(i % KPAD);
  if (r < N_IN) Win_bf[i] = (c < DIN) ? f2bf(Win[(size_t)r * DIN + c]) : (unsigned short)0;
  else {
    int rr = r - N_IN;
    X_bf[(size_t)rr * KPAD + c] = (c < DIN) ? f2bf(x[(size_t)rr * DIN + c]) : (unsigned short)0;
  }
}

// ---------- 128x128 GEMM core: A 3-ring / B 2-ring, vmcnt(4) steady ----------
__device__ __forceinline__ void gemm_core(
    const unsigned short* __restrict__ Ag, const unsigned short* __restrict__ Bg,
    int K, int bm, int bn, unsigned short* lds, f32x4 acc[4][4])
{
  const int t    = threadIdx.x;
  const int lane = t & 63;
  const int wave = t >> 6;           // 0..3
  const int wm   = wave >> 1;        // 64-row band
  const int wn   = wave & 1;         // 64-col band
  const int l15  = lane & 15;
  const int lkb  = (lane >> 4) * 16; // byte offset of k-group within row

  const int srow = t >> 3;
  const int sb   = ((t & 7) * 16) ^ ((srow & 7) << 4);
  const unsigned aG0 = (unsigned)((bm + srow) * K + (sb >> 1));
  const unsigned bG0 = (unsigned)((bn + srow) * K + (sb >> 1));

  auto STAGE_A = [&](int sA, int k0) {             // 4 async16/thread
    unsigned short* s = lds + sA * ASLE;
#pragma unroll
    for (int j = 0; j < 4; ++j)
      async16(Ag + aG0 + (unsigned)(j * 32 * K + k0), s + t * 8 + j * 2048);
  };
  auto STAGE_B = [&](int sB, int k0) {             // 4 async16/thread
    unsigned short* s = lds + BOFF + sB * ASLE;
#pragma unroll
    for (int j = 0; j < 4; ++j)
      async16(Bg + bG0 + (unsigned)(j * 32 * K + k0), s + t * 8 + j * 2048);
  };

  int aRd[2][4], bRd[2][4];
#pragma unroll
  for (int kk = 0; kk < 2; ++kk)
#pragma unroll
    for (int i = 0; i < 4; ++i) {
      const int ra = wm * 64 + i * 16 + l15;
      aRd[kk][i] = (ra * 128 + ((kk * 64 + lkb) ^ ((ra & 7) << 4))) >> 1;
      const int rb = wn * 64 + i * 16 + l15;
      bRd[kk][i] = (rb * 128 + ((kk * 64 + lkb) ^ ((rb & 7) << 4))) >> 1;
    }

  const int nt = K >> 6;
  // prologue: A(0), B(0), A(1) -> 12 loads in flight
  STAGE_A(0, 0);
  STAGE_B(0, 0);
  if (nt > 1) STAGE_A(1, 64);

  int sA = 0, sA2 = 2, sB = 0;       // kt%3, (kt+2)%3, kt&1
  for (int kt = 0; kt < nt; ++kt) {
    if (kt + 1 < nt) asm volatile("s_waitcnt vmcnt(4)" ::: "memory"); // A(kt)+B(kt) done, A(kt+1) rides
    else             asm volatile("s_waitcnt vmcnt(0)" ::: "memory");
    __builtin_amdgcn_s_barrier();                  // tile kt visible; old slots' reads retired
    if (kt + 1 < nt) STAGE_B(sB ^ 1, (kt + 1) << 6);
    if (kt + 2 < nt) STAGE_A(sA2, (kt + 2) << 6);
    const unsigned short* baseA = lds + sA * ASLE;
    const unsigned short* baseB = lds + BOFF + sB * ASLE;
    // preload ALL fragments for this tile, then one 32-MFMA cluster
    bf16x8 a[2][4], b[2][4];
#pragma unroll
    for (int kk = 0; kk < 2; ++kk) {
#pragma unroll
      for (int i = 0; i < 4; ++i) a[kk][i] = *reinterpret_cast<const bf16x8*>(baseA + aRd[kk][i]);
#pragma unroll
      for (int i = 0; i < 4; ++i) b[kk][i] = *reinterpret_cast<const bf16x8*>(baseB + bRd[kk][i]);
    }
    __builtin_amdgcn_s_setprio(1);
#pragma unroll
    for (int kk = 0; kk < 2; ++kk)
#pragma unroll
      for (int mi = 0; mi < 4; ++mi)
#pragma unroll
        for (int ni = 0; ni < 4; ++ni)
          acc[mi][ni] = __builtin_amdgcn_mfma_f32_16x16x32_bf16(a[kk][mi], b[kk][ni], acc[mi][ni], 0, 0, 0);
    __builtin_amdgcn_s_setprio(0);
    sA  = (sA  == 2) ? 0 : sA  + 1;
    sA2 = (sA2 == 2) ? 0 : sA2 + 1;
    sB ^= 1;
  }
}

// ---------- recurrent layer GEMM ----------
__global__ __launch_bounds__(256, 2) void k_gemm_layer(
    const unsigned short* __restrict__ A, const unsigned short* __restrict__ W,
    const float* __restrict__ bias, float* __restrict__ preact,
    unsigned short* __restrict__ Anext)
{
  __shared__ __align__(16) unsigned short lds[5 * ASLE];   // 80 KB
  const int bid = blockIdx.x;            // 512 blocks = 16 bm x 32 bn
  const int xcd = bid & 7;
  const int idx = bid >> 3;              // 0..63
  const int bm  = (idx >> 2) * 128;      // 16 m-bands
  const int bn  = (xcd * 4 + (idx & 3)) * 128;   // XCD owns 4 bn-bands (W L2-fit)
  f32x4 acc[4][4] = {};
  gemm_core(A, W, NH, bm, bn, lds, acc);

  const int lane = threadIdx.x & 63;
  const int wave = threadIdx.x >> 6;
  const int wm = (wave >> 1) * 64, wn = (wave & 1) * 64;
  const int l15 = lane & 15;
#pragma unroll
  for (int mi = 0; mi < 4; ++mi) {
    const int gm0 = bm + wm + mi * 16 + (lane >> 4) * 4;   // C/D: row=(lane>>4)*4+r
#pragma unroll
    for (int ni = 0; ni < 4; ++ni) {
      const int gn = bn + wn + ni * 16 + l15;              // C/D: col=lane&15
      const float bv = bias[gn];
#pragma unroll
      for (int r = 0; r < 4; ++r) {
        const int gm = gm0 + r;
        const float y = acc[mi][ni][r] + bv;
        if (gm < MB) preact[(size_t)gm * NH + gn] = y;
        Anext[(size_t)gm * NH + gn] = f2bf(y > 0.f ? y : 0.f);
      }
    }
  }
}

// ---------- input GEMM ----------
__global__ __launch_bounds__(256, 2) void k_gemm_in(
    const unsigned short* __restrict__ X, const unsigned short* __restrict__ W,
    const float* __restrict__ bias, float* __restrict__ preact0,
    unsigned short* __restrict__ A0)
{
  __shared__ __align__(16) unsigned short lds[5 * ASLE];
  const int bid = blockIdx.x;            // 512 blocks = 8 bm x 64 bn
  const int xcd = bid & 7;
  const int idx = bid >> 3;              // 0..63
  const int bm  = (idx >> 3) * 128;      // 8 m-bands
  const int bn  = (xcd * 8 + (idx & 7)) * 128;
  f32x4 acc[4][4] = {};
  gemm_core(X, W, KPAD, bm, bn, lds, acc);

  const int lane = threadIdx.x & 63;
  const int wave = threadIdx.x >> 6;
  const int wm = (wave >> 1) * 64, wn = (wave & 1) * 64;
  const int l15 = lane & 15;
#pragma unroll
  for (int mi = 0; mi < 4; ++mi) {
    const int gm0 = bm + wm + mi * 16 + (lane >> 4) * 4;
#pragma unroll
    for (int ni = 0; ni < 4; ++ni) {
      const int gn = bn + wn + ni * 16 + l15;
      const float bv = bias[gn];
#pragma unroll
      for (int r = 0; r < 4; ++r) {
        const int gm = gm0 + r;
        const float y = acc[mi][ni][r] + bv;
        const unsigned short rl = f2bf(y > 0.f ? y : 0.f);
        if (gn < NH) {                       // "a" stream
          preact0[(size_t)gm * NH + gn] = y;
          A0[(size_t)gm * NH + gn] = rl;
        } else {                             // "b" stream -> rows 1024..2047
          A0[(size_t)(MB + gm) * NH + (gn - NH)] = rl;
        }
      }
    }
  }
}

// ---------- final head: 256 blocks x 8 rows, vectorized loads ----------
__global__ __launch_bounds__(256) void k_final(
    const unsigned short* __restrict__ A, const float* __restrict__ Wf,
    const float* __restrict__ of, const float* __restrict__ bf_,
    float* __restrict__ out)
{
  __shared__ float red[4][NOUT];
  const int t = threadIdx.x;
  for (int rr = 0; rr < 8; ++rr) {
    const int m = blockIdx.x * 8 + rr;          // 0..2047
    float accj[NOUT];
#pragma unroll
    for (int j = 0; j < NOUT; ++j) accj[j] = 0.f;
    for (int k0 = t * 8; k0 < NH; k0 += 256 * 8) {
      const ushort8v av = *reinterpret_cast<const ushort8v*>(A + (size_t)m * NH + k0);
      const float4 o0 = *reinterpret_cast<const float4*>(of + k0);
      const float4 o1 = *reinterpret_cast<const float4*>(of + k0 + 4);
      float a[8];
      a[0] = bf2f(av[0]) * o0.x; a[1] = bf2f(av[1]) * o0.y;
      a[2] = bf2f(av[2]) * o0.z; a[3] = bf2f(av[3]) * o0.w;
      a[4] = bf2f(av[4]) * o1.x; a[5] = bf2f(av[5]) * o1.y;
      a[6] = bf2f(av[6]) * o1.z; a[7] = bf2f(av[7]) * o1.w;
#pragma unroll
      for (int j = 0; j < NOUT; ++j) {
        const float4 w0 = *reinterpret_cast<const float4*>(Wf + (size_t)j * NH + k0);
        const float4 w1 = *reinterpret_cast<const float4*>(Wf + (size_t)j * NH + k0 + 4);
        accj[j] += a[0]*w0.x + a[1]*w0.y + a[2]*w0.z + a[3]*w0.w
                 + a[4]*w1.x + a[5]*w1.y + a[6]*w1.z + a[7]*w1.w;
      }
    }
#pragma unroll
    for (int j = 0; j < NOUT; ++j) {
      float v = accj[j];
      for (int off = 32; off > 0; off >>= 1) v += __shfl_down(v, off);
      if ((t & 63) == 0) red[t >> 6][j] = v;
    }
    __syncthreads();
    if (t < NOUT)
      out[(size_t)m * NOUT + t] = red[0][t] + red[1][t] + red[2][t] + red[3][t] + bf_[t];
    __syncthreads();
  }
}

extern "C" void kernel_launch(void* const* d_in, const int* in_sizes, int n_in,
                              void* d_out, int out_size, void* d_ws, size_t ws_size,
                              hipStream_t stream) {
  const float* x     = (const float*)d_in[0];
  const float* W_in  = (const float*)d_in[1];
  const float* b_in  = (const float*)d_in[2];
  const float* keysp = (const float*)d_in[3];
  const float* W_sp  = (const float*)d_in[4];
  const float* b_sp  = (const float*)d_in[5];
  const float* keyf  = (const float*)d_in[6];
  const float* W_f   = (const float*)d_in[7];
  const float* b_f   = (const float*)d_in[8];

  float* out    = (float*)d_out;
  float* preact = out + (size_t)2 * MB * NOUT;  // 25 x 1024 x 4096

  char* ws = (char*)d_ws;
  unsigned short* Wsp_bf = (unsigned short*)ws;  ws += (size_t)NH * NH * 2;
  unsigned short* A0     = (unsigned short*)ws;  ws += (size_t)M2 * NH * 2;
  unsigned short* A1     = (unsigned short*)ws;  ws += (size_t)M2 * NH * 2;
  unsigned short* Win_bf = (unsigned short*)ws;  ws += (size_t)N_IN * KPAD * 2;
  unsigned short* X_bf   = (unsigned short*)ws;  ws += (size_t)MB * KPAD * 2;

  k_conv_wsp<<<(NH * (size_t)NH / 4 + 255) / 256, 256, 0, stream>>>(W_sp, keysp, Wsp_bf);
  k_conv_pad2<<<((size_t)(N_IN + MB) * KPAD + 255) / 256, 256, 0, stream>>>(
      W_in, x, Win_bf, X_bf);

  // input GEMM: M=1024, N=8192, K=832 -> 8*64 = 512 blocks
  k_gemm_in<<<512, 256, 0, stream>>>(X_bf, Win_bf, b_in, preact, A0);

  // 24 recurrent layers: M=2048, N=4096, K=4096 -> 16*32 = 512 blocks
  unsigned short* Ain = A0;
  unsigned short* Aout = A1;
  for (int tlay = 0; tlay < NLAYERS; ++tlay) {
    float* pre = preact + (size_t)(tlay + 1) * MB * NH;
    k_gemm_layer<<<512, 256, 0, stream>>>(Ain, Wsp_bf, b_sp, pre, Aout);
    unsigned short* tmp = Ain; Ain = Aout; Aout = tmp;
  }

  k_final<<<M2 / 8, 256, 0, stream>>>(Ain, W_f, keyf, b_f, out);
}